// Round 11
// baseline (527.572 us; speedup 1.0000x reference)
//
#include <hip/hip_runtime.h>
#include <hip/hip_bf16.h>

#define DIM   512
#define QKD   1024   // Q/K buffer row stride
#define HEADS 8
#define HD    64
#define NSEQ  4096
#define LDP   72    // 144B row stride, bank-stride 4 mod 32 -> conflict-free b128
#define LDPK  72
#define LDPV  136   // 272B stride, conflict-free b128
#define LDPM  136   // V repack tile [oc][m] row stride
#define SCALE_LOG2E 0.18033688011112042f   // 0.125 * log2(e), folded into Q

typedef float  f32x4  __attribute__((ext_vector_type(4)));
typedef __bf16 bf16x8 __attribute__((ext_vector_type(8)));
typedef __bf16 bf16x4 __attribute__((ext_vector_type(4)));
typedef short  s16x4  __attribute__((ext_vector_type(4)));

static __device__ inline f32x4 mfma32(bf16x8 a, bf16x8 b, f32x4 c) {
  return __builtin_amdgcn_mfma_f32_16x16x32_bf16(a, b, c, 0, 0, 0);
}
static __device__ inline s16x4 pack_bf16(f32x4 v) {
  bf16x4 b = __builtin_convertvector(v, bf16x4);
  return __builtin_bit_cast(s16x4, b);
}
static __device__ inline bf16x8 cvt8(f32x4 a, f32x4 b) {
  return __builtin_shufflevector(__builtin_convertvector(a, bf16x4),
                                 __builtin_convertvector(b, bf16x4),
                                 0, 1, 2, 3, 4, 5, 6, 7);
}

// 128x128-tile GEMM, register-prefetch; fp32 inputs converted to bf16 AT LOAD
// TIME (prefetch held as bf16x8: 32 fewer VGPRs than f32x4 -> 3 blocks/CU).
// nt 0..7: Q/K -> qkC[m][1024] (Q scaled). nt 8..11: V -> Vt[bh][d][perm(n)].
__global__ __launch_bounds__(256, 3) void gemm_qkv(const float* __restrict__ A,
                                                   const float* __restrict__ Bw,
                                                   const float* __restrict__ bias,
                                                   __bf16* __restrict__ C,
                                                   __bf16* __restrict__ Vt) {
  const int nt = blockIdx.x;   // 0..11
  const int mt = blockIdx.y;   // 0..63
  __shared__ __align__(16) char smem[36864];
  __bf16* As = (__bf16*)smem;                    // 128*LDP = 18432 B
  __bf16* Bs = (__bf16*)(smem + 18432);          // 18432 B
  __bf16* T  = (__bf16*)smem;                    // 128*LDPM = 34816 B (epilogue)
  const int tid = threadIdx.x, w = tid >> 6, lane = tid & 63;
  const int l16 = lane & 15, quad = lane >> 4;

  int row[4], c8[4];
#pragma unroll
  for (int i = 0; i < 4; ++i) { int ch = tid + i * 256; row[i] = ch >> 3; c8[i] = (ch & 7) << 3; }

  bf16x8 pa[4], pb[4];
#pragma unroll
  for (int i = 0; i < 4; ++i) {
    const float* ap = A + (size_t)(mt * 128 + row[i]) * DIM + c8[i];
    const float* bp = Bw + (size_t)(nt * 128 + row[i]) * DIM + c8[i];
    pa[i] = cvt8(*(const f32x4*)ap, *(const f32x4*)(ap + 4));
    pb[i] = cvt8(*(const f32x4*)bp, *(const f32x4*)(bp + 4));
  }

  f32x4 acc[2][8] = {};
  for (int kt = 0; kt < 8; ++kt) {
    __syncthreads();
#pragma unroll
    for (int i = 0; i < 4; ++i) {
      *(bf16x8*)(As + row[i] * LDP + c8[i]) = pa[i];
      *(bf16x8*)(Bs + row[i] * LDP + c8[i]) = pb[i];
    }
    __syncthreads();
    if (kt < 7) {
#pragma unroll
      for (int i = 0; i < 4; ++i) {
        const float* ap = A + (size_t)(mt * 128 + row[i]) * DIM + (kt + 1) * 64 + c8[i];
        const float* bp = Bw + (size_t)(nt * 128 + row[i]) * DIM + (kt + 1) * 64 + c8[i];
        pa[i] = cvt8(*(const f32x4*)ap, *(const f32x4*)(ap + 4));
        pb[i] = cvt8(*(const f32x4*)bp, *(const f32x4*)(bp + 4));
      }
    }
#pragma unroll
    for (int c = 0; c < 2; ++c) {
      bf16x8 a[2];
#pragma unroll
      for (int mtt = 0; mtt < 2; ++mtt)
        a[mtt] = *(const bf16x8*)(As + (w * 32 + mtt * 16 + l16) * LDP + quad * 8 + c * 32);
#pragma unroll
      for (int ct = 0; ct < 8; ++ct) {
        bf16x8 bb = *(const bf16x8*)(Bs + (ct * 16 + l16) * LDP + quad * 8 + c * 32);
#pragma unroll
        for (int mtt = 0; mtt < 2; ++mtt)
          acc[mtt][ct] = mfma32(a[mtt], bb, acc[mtt][ct]);
      }
    }
  }

  if (nt < 8) {
    const float sc = (nt < 4) ? SCALE_LOG2E : 1.0f;
#pragma unroll
    for (int ct = 0; ct < 8; ++ct) {
      int oc = nt * 128 + ct * 16 + l16;
      float bv = bias[oc];
#pragma unroll
      for (int mtt = 0; mtt < 2; ++mtt)
#pragma unroll
        for (int r = 0; r < 4; ++r) {
          int mrow = mt * 128 + w * 32 + mtt * 16 + quad * 4 + r;
          C[(size_t)mrow * QKD + oc] = (__bf16)((acc[mtt][ct][r] + bv) * sc);
        }
    }
  } else {
    // V epilogue: bias, repack [oc_l][m] in LDS, permute-in-registers, then
    // contiguous b128 stores of the key-permuted 64-blocks.
    __syncthreads();
#pragma unroll
    for (int ct = 0; ct < 8; ++ct) {
      int oc_l = ct * 16 + l16;
      float bv = bias[1024 + (nt - 8) * 128 + oc_l];
#pragma unroll
      for (int mtt = 0; mtt < 2; ++mtt) {
        f32x4 v = acc[mtt][ct];
#pragma unroll
        for (int r = 0; r < 4; ++r) v[r] += bv;
        *(bf16x4*)(T + oc_l * LDPM + w * 32 + mtt * 16 + quad * 4) =
            __builtin_convertvector(v, bf16x4);
      }
    }
    __syncthreads();
    const int oc_l = tid & 127;        // 0..127
    const int mh = (tid >> 7) * 64;    // 0 / 64 : one 64-key block
    const int d = oc_l & 63;
    const int h = 2 * (nt - 8) + (oc_l >> 6);
    const int n0 = mt * 128 + mh;
    const int b = n0 >> 12;
    bf16x8 o[8];
#pragma unroll
    for (int j = 0; j < 8; ++j)
      o[j] = *(const bf16x8*)(T + oc_l * LDPM + mh + j * 8);
    // pos = 8c+e; key = (g2*2+m)*16 + u*4 + jj, g2=c>>2,u=c&3,m=e>>2,jj=e&3
    bf16x8 oc8[8];
#pragma unroll
    for (int c = 0; c < 8; ++c)
#pragma unroll
      for (int e = 0; e < 8; ++e)
        oc8[c][e] = o[(c >> 2) * 4 + (e >> 2) * 2 + ((c & 3) >> 1)][(c & 1) * 4 + (e & 3)];
    __bf16* dst = Vt + ((size_t)(b * HEADS + h) * HD + d) * NSEQ + (n0 & 4095);
#pragma unroll
    for (int c = 0; c < 8; ++c) *(bf16x8*)(dst + c * 8) = oc8[c];
  }
}

// 128x64-tile GEMM, fp32 output, proj_w converted to bf16 at load time.
__global__ __launch_bounds__(256, 3) void gemm_proj(const __bf16* __restrict__ A,
                                                    const float* __restrict__ Bw,
                                                    const float* __restrict__ bias,
                                                    float* __restrict__ C) {
  const int nt = blockIdx.x;   // 0..7
  const int mt = blockIdx.y;   // 0..63
  __shared__ __bf16 As[128 * LDP];
  __shared__ __bf16 Bs[64 * LDP];
  const int tid = threadIdx.x, w = tid >> 6, lane = tid & 63;
  const int l16 = lane & 15, quad = lane >> 4;

  int arow[4], ac8[4], brow[2], bc8[2];
#pragma unroll
  for (int i = 0; i < 4; ++i) { int ch = tid + i * 256; arow[i] = ch >> 3; ac8[i] = (ch & 7) << 3; }
#pragma unroll
  for (int i = 0; i < 2; ++i) { int ch = tid + i * 256; brow[i] = ch >> 3; bc8[i] = (ch & 7) << 3; }

  bf16x8 pa[4], pb[2];
#pragma unroll
  for (int i = 0; i < 4; ++i)
    pa[i] = *(const bf16x8*)(A + (size_t)(mt * 128 + arow[i]) * DIM + ac8[i]);
#pragma unroll
  for (int i = 0; i < 2; ++i) {
    const float* bp = Bw + (size_t)(nt * 64 + brow[i]) * DIM + bc8[i];
    pb[i] = cvt8(*(const f32x4*)bp, *(const f32x4*)(bp + 4));
  }

  f32x4 acc[2][4] = {};
  for (int kt = 0; kt < 8; ++kt) {
    __syncthreads();
#pragma unroll
    for (int i = 0; i < 4; ++i) *(bf16x8*)(As + arow[i] * LDP + ac8[i]) = pa[i];
#pragma unroll
    for (int i = 0; i < 2; ++i) *(bf16x8*)(Bs + brow[i] * LDP + bc8[i]) = pb[i];
    __syncthreads();
    if (kt < 7) {
#pragma unroll
      for (int i = 0; i < 4; ++i)
        pa[i] = *(const bf16x8*)(A + (size_t)(mt * 128 + arow[i]) * DIM + (kt + 1) * 64 + ac8[i]);
#pragma unroll
      for (int i = 0; i < 2; ++i) {
        const float* bp = Bw + (size_t)(nt * 64 + brow[i]) * DIM + (kt + 1) * 64 + bc8[i];
        pb[i] = cvt8(*(const f32x4*)bp, *(const f32x4*)(bp + 4));
      }
    }
#pragma unroll
    for (int c = 0; c < 2; ++c) {
      bf16x8 a[2];
#pragma unroll
      for (int mtt = 0; mtt < 2; ++mtt)
        a[mtt] = *(const bf16x8*)(As + (w * 32 + mtt * 16 + l16) * LDP + quad * 8 + c * 32);
#pragma unroll
      for (int ct = 0; ct < 4; ++ct) {
        bf16x8 bb = *(const bf16x8*)(Bs + (ct * 16 + l16) * LDP + quad * 8 + c * 32);
#pragma unroll
        for (int mtt = 0; mtt < 2; ++mtt)
          acc[mtt][ct] = mfma32(a[mtt], bb, acc[mtt][ct]);
      }
    }
  }
#pragma unroll
  for (int ct = 0; ct < 4; ++ct) {
    int oc = nt * 64 + ct * 16 + l16;
    float bv = bias[oc];
#pragma unroll
    for (int mtt = 0; mtt < 2; ++mtt)
#pragma unroll
      for (int r = 0; r < 4; ++r) {
        int mrow = mt * 128 + w * 32 + mtt * 16 + quad * 4 + r;
        C[(size_t)mrow * DIM + oc] = acc[mtt][ct][r] + bv;
      }
  }
}

// Flash attention v10: mt=4 (R8 per-wave efficiency) + 2 blocks/CU. 512-thread
// block = two 4-wave key-split groups; grid (16 bh, 16 qt) = 256 blocks; LDS
// shaved to 71680 B (epilogue exchange done in two 40 KB mt-halves) so TWO
// blocks fit per CU (143360 <= 163840) -> 16 waves/CU for pipe overlap.
__global__ __launch_bounds__(512, 4) void attn_fused(const __bf16* __restrict__ QKV,
                                                     const __bf16* __restrict__ Vtp,
                                                     __bf16* __restrict__ Og) {
  const int bh = blockIdx.x;   // 0..15
  const int qt = blockIdx.y;   // 0..15 (256 q rows)
  const int b = bh >> 3, h = bh & 7;

  __shared__ __align__(16) char smem[71680];
  __bf16* KsAll  = (__bf16*)smem;               // [2][128*LDPK] = 36864 B
  __bf16* VtsAll = (__bf16*)(smem + 36864);     // [2][64*LDPV]  = 34816 B
  float*  Oex    = (float*)smem;                // 40960 B (epilogue overlay)

  const int tid = threadIdx.x, w = tid >> 6, lane = tid & 63;
  const int wg = w & 3, grp = w >> 2;
  const int l16 = lane & 15, quad = lane >> 4;
  const int g256 = tid & 255;

  __bf16* Ks  = KsAll + grp * (128 * LDPK);
  __bf16* Vts = VtsAll + grp * (64 * LDPV);

  const __bf16* Qb = QKV + (size_t)(b * NSEQ + qt * 256) * QKD + h * 64;
  const __bf16* Kb = QKV + ((size_t)b * NSEQ + (size_t)grp * 2048) * QKD + 512 + h * 64;
  const __bf16* Vp = Vtp + (size_t)bh * HD * NSEQ + grp * 2048;

  bf16x8 aq[4][2];
#pragma unroll
  for (int mt = 0; mt < 4; ++mt)
#pragma unroll
    for (int c = 0; c < 2; ++c)
      aq[mt][c] = *(const bf16x8*)(Qb + (size_t)(wg * 64 + mt * 16 + l16) * QKD +
                                   quad * 8 + c * 32);

  int krow[4], kc8[4], vd[4], vp8[4];
#pragma unroll
  for (int i = 0; i < 4; ++i) {
    int ch = g256 + i * 256;
    krow[i] = ch >> 3; kc8[i] = (ch & 7) << 3;
    vd[i] = ch >> 4;   vp8[i] = (ch & 15) << 3;
  }

  bf16x8 kreg[4], vreg[4];
#pragma unroll
  for (int i = 0; i < 4; ++i) {
    kreg[i] = *(const bf16x8*)(Kb + (size_t)krow[i] * QKD + kc8[i]);
    vreg[i] = *(const bf16x8*)(Vp + (size_t)vd[i] * NSEQ + vp8[i]);
  }

  bf16x8 ones;
#pragma unroll
  for (int j = 0; j < 8; ++j) ones[j] = (__bf16)1.0f;

  f32x4 Oacc[4][5] = {};   // dt 0..3 = O, dt 4 = l (ones-column)

  for (int kt = 0; kt < 16; ++kt) {
    __syncthreads();
#pragma unroll
    for (int i = 0; i < 4; ++i) {
      *(bf16x8*)(Ks + krow[i] * LDPK + kc8[i]) = kreg[i];
      *(bf16x8*)(Vts + vd[i] * LDPV + vp8[i]) = vreg[i];
    }
    __syncthreads();

    if (kt + 1 < 16) {
      const __bf16* Kn = Kb + (size_t)(kt + 1) * 128 * QKD;
      const __bf16* Vn = Vp + (size_t)(kt + 1) * 128;
#pragma unroll
      for (int i = 0; i < 4; ++i) {
        kreg[i] = *(const bf16x8*)(Kn + (size_t)krow[i] * QKD + kc8[i]);
        vreg[i] = *(const bf16x8*)(Vn + (size_t)vd[i] * NSEQ + vp8[i]);
      }
    }

#pragma unroll
    for (int g = 0; g < 4; ++g) {
      bf16x8 kb[2][2];
#pragma unroll
      for (int e = 0; e < 2; ++e)
#pragma unroll
        for (int c = 0; c < 2; ++c)
          kb[e][c] = *(const bf16x8*)(Ks + ((2 * g + e) * 16 + l16) * LDPK +
                                      quad * 8 + c * 32);
      bf16x8 ap[4];
#pragma unroll
      for (int mt = 0; mt < 4; ++mt) {
        f32x4 a0 = {}, a1 = {};
        a0 = mfma32(kb[0][0], aq[mt][0], a0);
        a0 = mfma32(kb[0][1], aq[mt][1], a0);
        a1 = mfma32(kb[1][0], aq[mt][0], a1);
        a1 = mfma32(kb[1][1], aq[mt][1], a1);
        f32x4 e0, e1;
#pragma unroll
        for (int r = 0; r < 4; ++r) {
          e0[r] = __builtin_amdgcn_exp2f(a0[r]);
          e1[r] = __builtin_amdgcn_exp2f(a1[r]);
        }
        ap[mt] = __builtin_bit_cast(bf16x8,
            __builtin_shufflevector(pack_bf16(e0), pack_bf16(e1), 0, 1, 2, 3, 4, 5, 6, 7));
      }
#pragma unroll
      for (int dt = 0; dt < 4; ++dt) {
        bf16x8 bv = *(const bf16x8*)(Vts + (dt * 16 + l16) * LDPV + g * 32 + quad * 8);
#pragma unroll
        for (int mt = 0; mt < 4; ++mt)
          Oacc[mt][dt] = mfma32(ap[mt], bv, Oacc[mt][dt]);
      }
#pragma unroll
      for (int mt = 0; mt < 4; ++mt)
        Oacc[mt][4] = mfma32(ap[mt], ones, Oacc[mt][4]);   // l column
    }
  }

  // combine group partials via LDS in TWO 40 KB halves (mt 0-1, then 2-3):
  // keeps smem at 71680 B so 2 blocks/CU fit.
  __syncthreads();
#pragma unroll
  for (int half = 0; half < 2; ++half) {
    if (grp == 1) {
#pragma unroll
      for (int mtl = 0; mtl < 2; ++mtl)
#pragma unroll
        for (int dt = 0; dt < 5; ++dt)
          *(f32x4*)(Oex + (((wg * 2 + mtl) * 5 + dt) << 8) + (lane << 2)) =
              Oacc[half * 2 + mtl][dt];
    }
    __syncthreads();
    if (grp == 0) {
#pragma unroll
      for (int mtl = 0; mtl < 2; ++mtl) {
        int mt = half * 2 + mtl;
#pragma unroll
        for (int dt = 0; dt < 5; ++dt)
          Oacc[mt][dt] += *(const f32x4*)(Oex + (((wg * 2 + mtl) * 5 + dt) << 8) + (lane << 2));
#pragma unroll
        for (int r = 0; r < 4; ++r) {
          float inv = 1.0f / Oacc[mt][4][r];
          int n = qt * 256 + wg * 64 + mt * 16 + quad * 4 + r;
          size_t base = ((size_t)b * NSEQ + n) * DIM + (size_t)h * HD;
#pragma unroll
          for (int dt = 0; dt < 4; ++dt)
            Og[base + dt * 16 + l16] = (__bf16)(Oacc[mt][dt][r] * inv);
        }
      }
    }
    __syncthreads();
  }
}

extern "C" void kernel_launch(void* const* d_in, const int* in_sizes, int n_in,
                              void* d_out, int out_size, void* d_ws, size_t ws_size,
                              hipStream_t stream) {
  const float* x      = (const float*)d_in[0];   // [2,4096,512]
  const float* qkv_w  = (const float*)d_in[1];   // [1536,512]
  const float* qkv_b  = (const float*)d_in[2];   // [1536]
  const float* proj_w = (const float*)d_in[3];   // [512,512]
  const float* proj_b = (const float*)d_in[4];   // [512]
  float* out = (float*)d_out;                    // [2,4096,512] fp32

  char* ws = (char*)d_ws;
  __bf16* Vtw = (__bf16*)(ws);                   // 8 MB  [B,H,HD,N] permuted
  __bf16* qkC = (__bf16*)(ws + 8388608);         // 16 MB [8192][1024] Q|K
  __bf16* Ob  = (__bf16*)(ws + 25165824);        // 8 MB  context [m][512]
  // total 33,554,432 B

  gemm_qkv<<<dim3(12, 64), 256, 0, stream>>>(x, qkv_w, qkv_b, qkC, Vtw);
  attn_fused<<<dim3(16, 16), 512, 0, stream>>>(qkC, Vtw, Ob);
  gemm_proj<<<dim3(8, 64), 256, 0, stream>>>(Ob, proj_w, proj_b, out);
}

// Round 12
// 187.237 us; speedup vs baseline: 2.8177x; 2.8177x over previous
//
#include <hip/hip_runtime.h>
#include <hip/hip_bf16.h>

#define DIM   512
#define QKD   1024   // Q/K buffer row stride
#define HEADS 8
#define HD    64
#define NSEQ  4096
#define LDP   72    // 144B row stride, bank-stride 4 mod 32 -> conflict-free b128
#define LDPK  72
#define LDPV  136   // 272B stride, conflict-free b128
#define LDPM  136   // V repack tile [oc][m] row stride
#define SCALE_LOG2E 0.18033688011112042f   // 0.125 * log2(e), folded into Q

typedef float  f32x4  __attribute__((ext_vector_type(4)));
typedef __bf16 bf16x8 __attribute__((ext_vector_type(8)));
typedef __bf16 bf16x4 __attribute__((ext_vector_type(4)));
typedef short  s16x4  __attribute__((ext_vector_type(4)));

static __device__ inline f32x4 mfma32(bf16x8 a, bf16x8 b, f32x4 c) {
  return __builtin_amdgcn_mfma_f32_16x16x32_bf16(a, b, c, 0, 0, 0);
}
static __device__ inline s16x4 pack_bf16(f32x4 v) {
  bf16x4 b = __builtin_convertvector(v, bf16x4);
  return __builtin_bit_cast(s16x4, b);
}
static __device__ inline bf16x8 cvt8(f32x4 a, f32x4 b) {
  return __builtin_shufflevector(__builtin_convertvector(a, bf16x4),
                                 __builtin_convertvector(b, bf16x4),
                                 0, 1, 2, 3, 4, 5, 6, 7);
}

// 128x128-tile GEMM, register-prefetch; fp32 inputs converted to bf16 at load
// time. nt 0..7: Q/K -> qkC[m][1024] (Q scaled). nt 8..11: V -> Vt[bh][d][perm(n)].
__global__ __launch_bounds__(256, 3) void gemm_qkv(const float* __restrict__ A,
                                                   const float* __restrict__ Bw,
                                                   const float* __restrict__ bias,
                                                   __bf16* __restrict__ C,
                                                   __bf16* __restrict__ Vt) {
  const int nt = blockIdx.x;   // 0..11
  const int mt = blockIdx.y;   // 0..63
  __shared__ __align__(16) char smem[36864];
  __bf16* As = (__bf16*)smem;                    // 128*LDP = 18432 B
  __bf16* Bs = (__bf16*)(smem + 18432);          // 18432 B
  __bf16* T  = (__bf16*)smem;                    // 128*LDPM = 34816 B (epilogue)
  const int tid = threadIdx.x, w = tid >> 6, lane = tid & 63;
  const int l16 = lane & 15, quad = lane >> 4;

  int row[4], c8[4];
#pragma unroll
  for (int i = 0; i < 4; ++i) { int ch = tid + i * 256; row[i] = ch >> 3; c8[i] = (ch & 7) << 3; }

  bf16x8 pa[4], pb[4];
#pragma unroll
  for (int i = 0; i < 4; ++i) {
    const float* ap = A + (size_t)(mt * 128 + row[i]) * DIM + c8[i];
    const float* bp = Bw + (size_t)(nt * 128 + row[i]) * DIM + c8[i];
    pa[i] = cvt8(*(const f32x4*)ap, *(const f32x4*)(ap + 4));
    pb[i] = cvt8(*(const f32x4*)bp, *(const f32x4*)(bp + 4));
  }

  f32x4 acc[2][8] = {};
  for (int kt = 0; kt < 8; ++kt) {
    __syncthreads();
#pragma unroll
    for (int i = 0; i < 4; ++i) {
      *(bf16x8*)(As + row[i] * LDP + c8[i]) = pa[i];
      *(bf16x8*)(Bs + row[i] * LDP + c8[i]) = pb[i];
    }
    __syncthreads();
    if (kt < 7) {
#pragma unroll
      for (int i = 0; i < 4; ++i) {
        const float* ap = A + (size_t)(mt * 128 + row[i]) * DIM + (kt + 1) * 64 + c8[i];
        const float* bp = Bw + (size_t)(nt * 128 + row[i]) * DIM + (kt + 1) * 64 + c8[i];
        pa[i] = cvt8(*(const f32x4*)ap, *(const f32x4*)(ap + 4));
        pb[i] = cvt8(*(const f32x4*)bp, *(const f32x4*)(bp + 4));
      }
    }
#pragma unroll
    for (int c = 0; c < 2; ++c) {
      bf16x8 a[2];
#pragma unroll
      for (int mtt = 0; mtt < 2; ++mtt)
        a[mtt] = *(const bf16x8*)(As + (w * 32 + mtt * 16 + l16) * LDP + quad * 8 + c * 32);
#pragma unroll
      for (int ct = 0; ct < 8; ++ct) {
        bf16x8 bb = *(const bf16x8*)(Bs + (ct * 16 + l16) * LDP + quad * 8 + c * 32);
#pragma unroll
        for (int mtt = 0; mtt < 2; ++mtt)
          acc[mtt][ct] = mfma32(a[mtt], bb, acc[mtt][ct]);
      }
    }
  }

  if (nt < 8) {
    const float sc = (nt < 4) ? SCALE_LOG2E : 1.0f;
#pragma unroll
    for (int ct = 0; ct < 8; ++ct) {
      int oc = nt * 128 + ct * 16 + l16;
      float bv = bias[oc];
#pragma unroll
      for (int mtt = 0; mtt < 2; ++mtt)
#pragma unroll
        for (int r = 0; r < 4; ++r) {
          int mrow = mt * 128 + w * 32 + mtt * 16 + quad * 4 + r;
          C[(size_t)mrow * QKD + oc] = (__bf16)((acc[mtt][ct][r] + bv) * sc);
        }
    }
  } else {
    // V epilogue: bias, repack [oc_l][m] in LDS, permute-in-registers, then
    // contiguous b128 stores of the key-permuted 64-blocks.
    __syncthreads();
#pragma unroll
    for (int ct = 0; ct < 8; ++ct) {
      int oc_l = ct * 16 + l16;
      float bv = bias[1024 + (nt - 8) * 128 + oc_l];
#pragma unroll
      for (int mtt = 0; mtt < 2; ++mtt) {
        f32x4 v = acc[mtt][ct];
#pragma unroll
        for (int r = 0; r < 4; ++r) v[r] += bv;
        *(bf16x4*)(T + oc_l * LDPM + w * 32 + mtt * 16 + quad * 4) =
            __builtin_convertvector(v, bf16x4);
      }
    }
    __syncthreads();
    const int oc_l = tid & 127;        // 0..127
    const int mh = (tid >> 7) * 64;    // 0 / 64 : one 64-key block
    const int d = oc_l & 63;
    const int h = 2 * (nt - 8) + (oc_l >> 6);
    const int n0 = mt * 128 + mh;
    const int b = n0 >> 12;
    bf16x8 o[8];
#pragma unroll
    for (int j = 0; j < 8; ++j)
      o[j] = *(const bf16x8*)(T + oc_l * LDPM + mh + j * 8);
    // pos = 8c+e; key = (g2*2+m)*16 + u*4 + jj, g2=c>>2,u=c&3,m=e>>2,jj=e&3
    bf16x8 oc8[8];
#pragma unroll
    for (int c = 0; c < 8; ++c)
#pragma unroll
      for (int e = 0; e < 8; ++e)
        oc8[c][e] = o[(c >> 2) * 4 + (e >> 2) * 2 + ((c & 3) >> 1)][(c & 1) * 4 + (e & 3)];
    __bf16* dst = Vt + ((size_t)(b * HEADS + h) * HD + d) * NSEQ + (n0 & 4095);
#pragma unroll
    for (int c = 0; c < 8; ++c) *(bf16x8*)(dst + c * 8) = oc8[c];
  }
}

// 128x64-tile GEMM, fp32 output, proj_w converted to bf16 at load time.
__global__ __launch_bounds__(256, 3) void gemm_proj(const __bf16* __restrict__ A,
                                                    const float* __restrict__ Bw,
                                                    const float* __restrict__ bias,
                                                    float* __restrict__ C) {
  const int nt = blockIdx.x;   // 0..7
  const int mt = blockIdx.y;   // 0..63
  __shared__ __bf16 As[128 * LDP];
  __shared__ __bf16 Bs[64 * LDP];
  const int tid = threadIdx.x, w = tid >> 6, lane = tid & 63;
  const int l16 = lane & 15, quad = lane >> 4;

  int arow[4], ac8[4], brow[2], bc8[2];
#pragma unroll
  for (int i = 0; i < 4; ++i) { int ch = tid + i * 256; arow[i] = ch >> 3; ac8[i] = (ch & 7) << 3; }
#pragma unroll
  for (int i = 0; i < 2; ++i) { int ch = tid + i * 256; brow[i] = ch >> 3; bc8[i] = (ch & 7) << 3; }

  bf16x8 pa[4], pb[2];
#pragma unroll
  for (int i = 0; i < 4; ++i)
    pa[i] = *(const bf16x8*)(A + (size_t)(mt * 128 + arow[i]) * DIM + ac8[i]);
#pragma unroll
  for (int i = 0; i < 2; ++i) {
    const float* bp = Bw + (size_t)(nt * 64 + brow[i]) * DIM + bc8[i];
    pb[i] = cvt8(*(const f32x4*)bp, *(const f32x4*)(bp + 4));
  }

  f32x4 acc[2][4] = {};
  for (int kt = 0; kt < 8; ++kt) {
    __syncthreads();
#pragma unroll
    for (int i = 0; i < 4; ++i) *(bf16x8*)(As + arow[i] * LDP + ac8[i]) = pa[i];
#pragma unroll
    for (int i = 0; i < 2; ++i) *(bf16x8*)(Bs + brow[i] * LDP + bc8[i]) = pb[i];
    __syncthreads();
    if (kt < 7) {
#pragma unroll
      for (int i = 0; i < 4; ++i)
        pa[i] = *(const bf16x8*)(A + (size_t)(mt * 128 + arow[i]) * DIM + (kt + 1) * 64 + ac8[i]);
#pragma unroll
      for (int i = 0; i < 2; ++i) {
        const float* bp = Bw + (size_t)(nt * 64 + brow[i]) * DIM + (kt + 1) * 64 + bc8[i];
        pb[i] = cvt8(*(const f32x4*)bp, *(const f32x4*)(bp + 4));
      }
    }
#pragma unroll
    for (int c = 0; c < 2; ++c) {
      bf16x8 a[2];
#pragma unroll
      for (int mtt = 0; mtt < 2; ++mtt)
        a[mtt] = *(const bf16x8*)(As + (w * 32 + mtt * 16 + l16) * LDP + quad * 8 + c * 32);
#pragma unroll
      for (int ct = 0; ct < 4; ++ct) {
        bf16x8 bb = *(const bf16x8*)(Bs + (ct * 16 + l16) * LDP + quad * 8 + c * 32);
#pragma unroll
        for (int mtt = 0; mtt < 2; ++mtt)
          acc[mtt][ct] = mfma32(a[mtt], bb, acc[mtt][ct]);
      }
    }
  }
#pragma unroll
  for (int ct = 0; ct < 4; ++ct) {
    int oc = nt * 64 + ct * 16 + l16;
    float bv = bias[oc];
#pragma unroll
    for (int mtt = 0; mtt < 2; ++mtt)
#pragma unroll
      for (int r = 0; r < 4; ++r) {
        int mrow = mt * 128 + w * 32 + mtt * 16 + quad * 4 + r;
        C[(size_t)mrow * DIM + oc] = acc[mtt][ct][r] + bv;
      }
  }
}

// Flash attention v11 = v10 structure with __launch_bounds__(512, 2):
// (512,4) empirically clamps VGPR to 64 -> massive scratch spill (R11).
// (512,2) compiles this body to ~120 VGPRs (R9) <= 128, so 4 waves/SIMD are
// VGPR-feasible; LDS 71680 B x 2 = 143 KB <= 160 KB -> 2 blocks/CU.
__global__ __launch_bounds__(512, 2) void attn_fused(const __bf16* __restrict__ QKV,
                                                     const __bf16* __restrict__ Vtp,
                                                     __bf16* __restrict__ Og) {
  const int bh = blockIdx.x;   // 0..15
  const int qt = blockIdx.y;   // 0..15 (256 q rows)
  const int b = bh >> 3, h = bh & 7;

  __shared__ __align__(16) char smem[71680];
  __bf16* KsAll  = (__bf16*)smem;               // [2][128*LDPK] = 36864 B
  __bf16* VtsAll = (__bf16*)(smem + 36864);     // [2][64*LDPV]  = 34816 B
  float*  Oex    = (float*)smem;                // 40960 B (epilogue overlay)

  const int tid = threadIdx.x, w = tid >> 6, lane = tid & 63;
  const int wg = w & 3, grp = w >> 2;
  const int l16 = lane & 15, quad = lane >> 4;
  const int g256 = tid & 255;

  __bf16* Ks  = KsAll + grp * (128 * LDPK);
  __bf16* Vts = VtsAll + grp * (64 * LDPV);

  const __bf16* Qb = QKV + (size_t)(b * NSEQ + qt * 256) * QKD + h * 64;
  const __bf16* Kb = QKV + ((size_t)b * NSEQ + (size_t)grp * 2048) * QKD + 512 + h * 64;
  const __bf16* Vp = Vtp + (size_t)bh * HD * NSEQ + grp * 2048;

  bf16x8 aq[4][2];
#pragma unroll
  for (int mt = 0; mt < 4; ++mt)
#pragma unroll
    for (int c = 0; c < 2; ++c)
      aq[mt][c] = *(const bf16x8*)(Qb + (size_t)(wg * 64 + mt * 16 + l16) * QKD +
                                   quad * 8 + c * 32);

  int krow[4], kc8[4], vd[4], vp8[4];
#pragma unroll
  for (int i = 0; i < 4; ++i) {
    int ch = g256 + i * 256;
    krow[i] = ch >> 3; kc8[i] = (ch & 7) << 3;
    vd[i] = ch >> 4;   vp8[i] = (ch & 15) << 3;
  }

  bf16x8 kreg[4], vreg[4];
#pragma unroll
  for (int i = 0; i < 4; ++i) {
    kreg[i] = *(const bf16x8*)(Kb + (size_t)krow[i] * QKD + kc8[i]);
    vreg[i] = *(const bf16x8*)(Vp + (size_t)vd[i] * NSEQ + vp8[i]);
  }

  bf16x8 ones;
#pragma unroll
  for (int j = 0; j < 8; ++j) ones[j] = (__bf16)1.0f;

  f32x4 Oacc[4][5] = {};   // dt 0..3 = O, dt 4 = l (ones-column)

  for (int kt = 0; kt < 16; ++kt) {
    __syncthreads();
#pragma unroll
    for (int i = 0; i < 4; ++i) {
      *(bf16x8*)(Ks + krow[i] * LDPK + kc8[i]) = kreg[i];
      *(bf16x8*)(Vts + vd[i] * LDPV + vp8[i]) = vreg[i];
    }
    __syncthreads();

    if (kt + 1 < 16) {
      const __bf16* Kn = Kb + (size_t)(kt + 1) * 128 * QKD;
      const __bf16* Vn = Vp + (size_t)(kt + 1) * 128;
#pragma unroll
      for (int i = 0; i < 4; ++i) {
        kreg[i] = *(const bf16x8*)(Kn + (size_t)krow[i] * QKD + kc8[i]);
        vreg[i] = *(const bf16x8*)(Vn + (size_t)vd[i] * NSEQ + vp8[i]);
      }
    }

#pragma unroll
    for (int g = 0; g < 4; ++g) {
      bf16x8 kb[2][2];
#pragma unroll
      for (int e = 0; e < 2; ++e)
#pragma unroll
        for (int c = 0; c < 2; ++c)
          kb[e][c] = *(const bf16x8*)(Ks + ((2 * g + e) * 16 + l16) * LDPK +
                                      quad * 8 + c * 32);
      bf16x8 ap[4];
#pragma unroll
      for (int mt = 0; mt < 4; ++mt) {
        f32x4 a0 = {}, a1 = {};
        a0 = mfma32(kb[0][0], aq[mt][0], a0);
        a0 = mfma32(kb[0][1], aq[mt][1], a0);
        a1 = mfma32(kb[1][0], aq[mt][0], a1);
        a1 = mfma32(kb[1][1], aq[mt][1], a1);
        f32x4 e0, e1;
#pragma unroll
        for (int r = 0; r < 4; ++r) {
          e0[r] = __builtin_amdgcn_exp2f(a0[r]);
          e1[r] = __builtin_amdgcn_exp2f(a1[r]);
        }
        ap[mt] = __builtin_bit_cast(bf16x8,
            __builtin_shufflevector(pack_bf16(e0), pack_bf16(e1), 0, 1, 2, 3, 4, 5, 6, 7));
      }
#pragma unroll
      for (int dt = 0; dt < 4; ++dt) {
        bf16x8 bv = *(const bf16x8*)(Vts + (dt * 16 + l16) * LDPV + g * 32 + quad * 8);
#pragma unroll
        for (int mt = 0; mt < 4; ++mt)
          Oacc[mt][dt] = mfma32(ap[mt], bv, Oacc[mt][dt]);
      }
#pragma unroll
      for (int mt = 0; mt < 4; ++mt)
        Oacc[mt][4] = mfma32(ap[mt], ones, Oacc[mt][4]);   // l column
    }
  }

  // combine group partials via LDS in TWO 40 KB halves (mt 0-1, then 2-3):
  // keeps smem at 71680 B so 2 blocks/CU fit.
  __syncthreads();
#pragma unroll
  for (int half = 0; half < 2; ++half) {
    if (grp == 1) {
#pragma unroll
      for (int mtl = 0; mtl < 2; ++mtl)
#pragma unroll
        for (int dt = 0; dt < 5; ++dt)
          *(f32x4*)(Oex + (((wg * 2 + mtl) * 5 + dt) << 8) + (lane << 2)) =
              Oacc[half * 2 + mtl][dt];
    }
    __syncthreads();
    if (grp == 0) {
#pragma unroll
      for (int mtl = 0; mtl < 2; ++mtl) {
        int mt = half * 2 + mtl;
#pragma unroll
        for (int dt = 0; dt < 5; ++dt)
          Oacc[mt][dt] += *(const f32x4*)(Oex + (((wg * 2 + mtl) * 5 + dt) << 8) + (lane << 2));
#pragma unroll
        for (int r = 0; r < 4; ++r) {
          float inv = 1.0f / Oacc[mt][4][r];
          int n = qt * 256 + wg * 64 + mt * 16 + quad * 4 + r;
          size_t base = ((size_t)b * NSEQ + n) * DIM + (size_t)h * HD;
#pragma unroll
          for (int dt = 0; dt < 4; ++dt)
            Og[base + dt * 16 + l16] = (__bf16)(Oacc[mt][dt][r] * inv);
        }
      }
    }
    __syncthreads();
  }
}

extern "C" void kernel_launch(void* const* d_in, const int* in_sizes, int n_in,
                              void* d_out, int out_size, void* d_ws, size_t ws_size,
                              hipStream_t stream) {
  const float* x      = (const float*)d_in[0];   // [2,4096,512]
  const float* qkv_w  = (const float*)d_in[1];   // [1536,512]
  const float* qkv_b  = (const float*)d_in[2];   // [1536]
  const float* proj_w = (const float*)d_in[3];   // [512,512]
  const float* proj_b = (const float*)d_in[4];   // [512]
  float* out = (float*)d_out;                    // [2,4096,512] fp32

  char* ws = (char*)d_ws;
  __bf16* Vtw = (__bf16*)(ws);                   // 8 MB  [B,H,HD,N] permuted
  __bf16* qkC = (__bf16*)(ws + 8388608);         // 16 MB [8192][1024] Q|K
  __bf16* Ob  = (__bf16*)(ws + 25165824);        // 8 MB  context [m][512]
  // total 33,554,432 B

  gemm_qkv<<<dim3(12, 64), 256, 0, stream>>>(x, qkv_w, qkv_b, qkC, Vtw);
  attn_fused<<<dim3(16, 16), 512, 0, stream>>>(qkC, Vtw, Ob);
  gemm_proj<<<dim3(8, 64), 256, 0, stream>>>(Ob, proj_w, proj_b, out);
}